// Round 6
// baseline (108.558 us; speedup 1.0000x reference)
//
#include <hip/hip_runtime.h>

#define NB 512
#define SLOTS 32
#define D 1024
#define D4 256           // float4 per row
#define CAP 64
#define TAU_INV 10.0f

// ---- kernel 0: zero the per-bucket counters ----
__global__ void k_zero(int* __restrict__ cnt) {
    if (threadIdx.x < NB) cnt[threadIdx.x] = 0;
}

// ---- kernel 1: build per-bucket token lists (list order nondeterministic;
//      per-token FP math below is list-order-invariant → deterministic out) ----
__global__ void k_build(const int* __restrict__ tids, int n,
                        int* __restrict__ cnt, int* __restrict__ list) {
    int i = blockIdx.x * 256 + threadIdx.x;
    if (i < n) {
        int b = tids[i] & (NB - 1);
        int p = atomicAdd(&cnt[b], 1);
        if (p < CAP) list[b * CAP + p] = i;
    }
}

// ---- kernel 2: BARRIER-FREE. grid = 2*NB blocks of 256 (4 waves).
//      bucket = blockIdx&511 keeps both halves of a bucket on the same XCD
//      (512 % 8 == 0). Each wave owns 2 tokens end-to-end in registers:
//      no LDS, no __syncthreads, no vmcnt(0) drains.
__global__ __launch_bounds__(256, 2)
void k_main(const float* __restrict__ query,    // [NT][D]
            const int*   __restrict__ tids,     // [NT]
            const float* __restrict__ skeys,    // [NB*SLOTS][D]
            const float* __restrict__ svals,    // [NB*SLOTS][D]
            const int*   __restrict__ stids,    // [NB*SLOTS]
            const float* __restrict__ centroid, // [NB][D]
            float*       __restrict__ out,      // [NT][D]
            const int*   __restrict__ cnt,
            const int*   __restrict__ list)
{
    const int bucket = blockIdx.x & (NB - 1);
    const int h      = blockIdx.x >> 9;        // 0/1
    const int lane   = threadIdx.x & 63;
    const int wid    = threadIdx.x >> 6;       // 0..3
    const int wslot  = h * 4 + wid;            // 0..7

    const int count = min(cnt[bucket], CAP);
    if (count == 0) return;

    // anchor row in regs (L2-hot: shared by both halves on same XCD)
    const float4* cb = (const float4*)(centroid + (size_t)bucket * D);
    float4 anc[4];
    #pragma unroll
    for (int j = 0; j < 4; ++j) anc[j] = cb[lane + 64 * j];
    // slot tid for this lane's slot (lane&31)
    const int slot_tid = stids[bucket * SLOTS + (lane & 31)];

    const float4* kb = (const float4*)(skeys + (size_t)bucket * SLOTS * D);
    const float4* vb = (const float4*)(svals + (size_t)bucket * SLOTS * D);

    for (int base = wslot * 2; base < count; base += 16) {
        const int  t1ok = (base + 1 < count);
        const int  tokA = list[bucket * CAP + base];
        const int  tokB = list[bucket * CAP + (t1ok ? base + 1 : base)];

        // ---- unified queries for both tokens, fully in registers ----
        float4 uq[2][4];
        int    ttid[2];
        #pragma unroll
        for (int tk = 0; tk < 2; ++tk) {
            const int tok = tk ? tokB : tokA;
            ttid[tk] = tids[tok];                       // uniform addr → broadcast
            const float4* q4 = (const float4*)(query + (size_t)tok * D);
            float4 qv[4];
            float ss = 0.f;
            #pragma unroll
            for (int j = 0; j < 4; ++j) {
                qv[j] = q4[lane + 64 * j];
                ss += qv[j].x*qv[j].x + qv[j].y*qv[j].y + qv[j].z*qv[j].z + qv[j].w*qv[j].w;
            }
            #pragma unroll
            for (int off = 32; off >= 1; off >>= 1) ss += __shfl_xor(ss, off);
            const float qn = 0.5f / fmaxf(sqrtf(ss), 1e-12f);   // folds ALPHA=0.5
            float ss2 = 0.f;
            #pragma unroll
            for (int j = 0; j < 4; ++j) {
                uq[tk][j].x = qv[j].x * qn + 0.5f * anc[j].x;
                uq[tk][j].y = qv[j].y * qn + 0.5f * anc[j].y;
                uq[tk][j].z = qv[j].z * qn + 0.5f * anc[j].z;
                uq[tk][j].w = qv[j].w * qn + 0.5f * anc[j].w;
                ss2 += uq[tk][j].x*uq[tk][j].x + uq[tk][j].y*uq[tk][j].y
                     + uq[tk][j].z*uq[tk][j].z + uq[tk][j].w*uq[tk][j].w;
            }
            #pragma unroll
            for (int off = 32; off >= 1; off >>= 1) ss2 += __shfl_xor(ss2, off);
            const float un = 1.0f / fmaxf(sqrtf(ss2), 1e-12f);
            #pragma unroll
            for (int j = 0; j < 4; ++j) {
                uq[tk][j].x *= un; uq[tk][j].y *= un;
                uq[tk][j].z *= un; uq[tk][j].w *= un;
            }
        }

        // ---- scores: stream 32 key rows; score for slot s parks in lane s ----
        float sc0 = 0.f, sc1 = 0.f;
        #pragma unroll 2
        for (int s = 0; s < SLOTS; ++s) {
            float4 k[4];
            #pragma unroll
            for (int j = 0; j < 4; ++j) k[j] = kb[s * D4 + lane + 64 * j];
            float d0 = 0.f, d1 = 0.f;
            #pragma unroll
            for (int j = 0; j < 4; ++j) {
                d0 += k[j].x*uq[0][j].x + k[j].y*uq[0][j].y + k[j].z*uq[0][j].z + k[j].w*uq[0][j].w;
                d1 += k[j].x*uq[1][j].x + k[j].y*uq[1][j].y + k[j].z*uq[1][j].z + k[j].w*uq[1][j].w;
            }
            #pragma unroll
            for (int off = 32; off >= 1; off >>= 1) {
                d0 += __shfl_xor(d0, off);
                d1 += __shfl_xor(d1, off);
            }
            sc0 = (lane == s) ? d0 : sc0;
            sc1 = (lane == s) ? d1 : sc1;
        }

        // ---- in-wave softmax + hard-match (lanes 0..31 hold slots) ----
        float p0, p1;
        {
            const bool live = (lane < 32);
            // token A
            float m = sc0;
            #pragma unroll
            for (int off = 16; off >= 1; off >>= 1) m = fmaxf(m, __shfl_xor(m, off));
            float e = live ? __expf((sc0 - m) * TAU_INV) : 0.f;
            float mf = (live && slot_tid == ttid[0]) ? 1.f : 0.f;
            float es = e, ms = mf;
            #pragma unroll
            for (int off = 16; off >= 1; off >>= 1) {
                es += __shfl_xor(es, off);
                ms += __shfl_xor(ms, off);
            }
            p0 = (ms > 0.f) ? mf / (ms + 1e-9f) : e / es;
            // token B
            float m2 = sc1;
            #pragma unroll
            for (int off = 16; off >= 1; off >>= 1) m2 = fmaxf(m2, __shfl_xor(m2, off));
            float e2 = live ? __expf((sc1 - m2) * TAU_INV) : 0.f;
            float mf2 = (live && slot_tid == ttid[1]) ? 1.f : 0.f;
            float es2 = e2, ms2 = mf2;
            #pragma unroll
            for (int off = 16; off >= 1; off >>= 1) {
                es2 += __shfl_xor(es2, off);
                ms2 += __shfl_xor(ms2, off);
            }
            p1 = (ms2 > 0.f) ? mf2 / (ms2 + 1e-9f) : e2 / es2;
        }

        // ---- values: stream 32 rows, reuse each row for both tokens ----
        float4 acc0[4], acc1[4];
        #pragma unroll
        for (int j = 0; j < 4; ++j) {
            acc0[j] = make_float4(0.f, 0.f, 0.f, 0.f);
            acc1[j] = make_float4(0.f, 0.f, 0.f, 0.f);
        }
        #pragma unroll 2
        for (int s = 0; s < SLOTS; ++s) {
            const float w0 = __shfl(p0, s);
            const float w1 = __shfl(p1, s);
            float4 v[4];
            #pragma unroll
            for (int j = 0; j < 4; ++j) v[j] = vb[s * D4 + lane + 64 * j];
            #pragma unroll
            for (int j = 0; j < 4; ++j) {
                acc0[j].x += w0 * v[j].x; acc0[j].y += w0 * v[j].y;
                acc0[j].z += w0 * v[j].z; acc0[j].w += w0 * v[j].w;
                acc1[j].x += w1 * v[j].x; acc1[j].y += w1 * v[j].y;
                acc1[j].z += w1 * v[j].z; acc1[j].w += w1 * v[j].w;
            }
        }

        float4* oA = (float4*)(out + (size_t)tokA * D);
        #pragma unroll
        for (int j = 0; j < 4; ++j) oA[lane + 64 * j] = acc0[j];
        if (t1ok) {
            float4* oB = (float4*)(out + (size_t)tokB * D);
            #pragma unroll
            for (int j = 0; j < 4; ++j) oB[lane + 64 * j] = acc1[j];
        }
    }
}

extern "C" void kernel_launch(void* const* d_in, const int* in_sizes, int n_in,
                              void* d_out, int out_size, void* d_ws, size_t ws_size,
                              hipStream_t stream) {
    const float* query    = (const float*)d_in[0];
    const int*   tids     = (const int*)  d_in[1];
    const float* skeys    = (const float*)d_in[2];
    const float* svals    = (const float*)d_in[3];
    const int*   stids    = (const int*)  d_in[4];
    const float* centroid = (const float*)d_in[5];
    float* out = (float*)d_out;
    const int n_tokens = in_sizes[1];

    int* cnt  = (int*)d_ws;             // [NB]
    int* list = cnt + NB;               // [NB*CAP]

    k_zero<<<1, NB, 0, stream>>>(cnt);
    k_build<<<(n_tokens + 255) / 256, 256, 0, stream>>>(tids, n_tokens, cnt, list);
    k_main<<<NB * 2, 256, 0, stream>>>(query, tids, skeys, svals, stids,
                                       centroid, out, cnt, list);
}